// Round 2
// baseline (256.876 us; speedup 1.0000x reference)
//
#include <hip/hip_runtime.h>

#define U_   2048
#define T_   200
#define S_   10
#define K_   20
#define H_   16
#define DU_  32
#define DE_  32
#define DIN_ 264   // 32 + 11 + 220 + 1

#define THREADS 256
#define POS_PER_BLK 512   // M=2 positions per thread

// async global->LDS, 16B per lane, linear dest (wave-uniform base + lane*16)
__device__ __forceinline__ void g2l16(const void* g, void* l) {
    __builtin_amdgcn_global_load_lds(
        (const __attribute__((address_space(1))) void*)g,
        (__attribute__((address_space(3))) void*)l, 16, 0, 0);
}

// ---------------------------------------------------------------------------
// Kernel 1: pre[pos,h] = b_rnn[h] + x[pos,:] . Wx[:,h]
// x = [emb(32) | q(10)+zero | f(200)+zeros | ctime]
// Coalesced staging of q/f through LDS; weights via wave-uniform scalar loads.
// ---------------------------------------------------------------------------
__global__ __launch_bounds__(THREADS) void k_pre(
    const float* __restrict__ q, const float* __restrict__ f,
    const int* __restrict__ docid, const float* __restrict__ ct,
    const float* __restrict__ emb, const float* __restrict__ Wx,
    const float* __restrict__ brnn, float* __restrict__ pre)
{
    __shared__ float fbuf[POS_PER_BLK * K_];     // 40 KB, single buffer
    const int t = threadIdx.x;
    const int tile = blockIdx.x * POS_PER_BLK;   // grid 800 exact
    const int p0 = tile + t, p1 = p0 + THREADS;

    // ---- stage q tile first (contiguous 512*40B = 1280 granules, 5 rounds) ----
    {
        const char* src = (const char*)(q + (size_t)tile * S_);
        char* dst = (char*)fbuf;
#pragma unroll
        for (int r = 0; r < 5; ++r) {
            int g = r * THREADS + t;
            g2l16(src + (size_t)g * 16, dst + g * 16);
        }
    }

    float acc0[H_], acc1[H_];
#pragma unroll
    for (int h = 0; h < H_; ++h) { float b = brnn[h]; acc0[h] = b; acc1[h] = b; }

    // ---- emb part (rows 0..31): direct gather, overlapped with q staging ----
    {
        const float4* e0 = (const float4*)(emb + (size_t)docid[p0] * DE_);
        const float4* e1 = (const float4*)(emb + (size_t)docid[p1] * DE_);
#pragma unroll
        for (int r = 0; r < DE_ / 4; ++r) {
            float4 a = e0[r], b = e1[r];
            const float* w = Wx + (r * 4) * H_;   // uniform -> s_load
#pragma unroll
            for (int h = 0; h < H_; ++h) {
                acc0[h] += a.x * w[h] + a.y * w[h + 16] + a.z * w[h + 32] + a.w * w[h + 48];
                acc1[h] += b.x * w[h] + b.y * w[h + 16] + b.z * w[h + 32] + b.w * w[h + 48];
            }
        }
    }

    // ---- ctime (row 263): coalesced 4B loads ----
    {
        float c0 = ct[p0], c1 = ct[p1];
        const float* w = Wx + (DIN_ - 1) * H_;
#pragma unroll
        for (int h = 0; h < H_; ++h) { acc0[h] += c0 * w[h]; acc1[h] += c1 * w[h]; }
    }

    __syncthreads();   // q staged (syncthreads drains vmcnt)

    // ---- q part (rows 32..41) ----
    {
        const float2* x0 = (const float2*)&fbuf[t * S_];
        const float2* x1 = (const float2*)&fbuf[(t + THREADS) * S_];
#pragma unroll
        for (int j = 0; j < 5; ++j) {
            float2 a = x0[j], b = x1[j];
            const float* w = Wx + (DE_ + 2 * j) * H_;
#pragma unroll
            for (int h = 0; h < H_; ++h) {
                acc0[h] += a.x * w[h] + a.y * w[h + 16];
                acc1[h] += b.x * w[h] + b.y * w[h + 16];
            }
        }
    }

    // ---- f parts: 10 slate-row chunks (rows 43+20c .. 43+20c+19) ----
    const char* fsrc = (const char*)f + (size_t)tile * (S_ * K_ * 4);
    for (int c = 0; c < S_; ++c) {
        __syncthreads();          // previous compute done before overwrite
        // stage: 512 pos x 80B = 2560 granules, 10 rounds; pos=g/5, sub=g%5
#pragma unroll
        for (int r = 0; r < 10; ++r) {
            int g = r * THREADS + t;
            int pos = g / 5, sub = g - pos * 5;
            g2l16(fsrc + (size_t)pos * 800 + c * 80 + sub * 16,
                  (char*)fbuf + (size_t)g * 16);
        }
        __syncthreads();          // staged visible
        const float4* x0 = (const float4*)&fbuf[t * K_];
        const float4* x1 = (const float4*)&fbuf[(t + THREADS) * K_];
        const float* wb = Wx + (DE_ + S_ + 1 + c * K_) * H_;   // uniform
#pragma unroll
        for (int j4 = 0; j4 < 5; ++j4) {
            float4 a = x0[j4], b = x1[j4];
            const float* w = wb + j4 * 4 * H_;
#pragma unroll
            for (int h = 0; h < H_; ++h) {
                acc0[h] += a.x * w[h] + a.y * w[h + 16] + a.z * w[h + 32] + a.w * w[h + 48];
                acc1[h] += b.x * w[h] + b.y * w[h + 16] + b.z * w[h + 32] + b.w * w[h + 48];
            }
        }
    }

    // ---- store pre ----
    {
        float4* o0 = (float4*)(pre + (size_t)p0 * H_);
        float4* o1 = (float4*)(pre + (size_t)p1 * H_);
        o0[0] = make_float4(acc0[0], acc0[1], acc0[2], acc0[3]);
        o0[1] = make_float4(acc0[4], acc0[5], acc0[6], acc0[7]);
        o0[2] = make_float4(acc0[8], acc0[9], acc0[10], acc0[11]);
        o0[3] = make_float4(acc0[12], acc0[13], acc0[14], acc0[15]);
        o1[0] = make_float4(acc1[0], acc1[1], acc1[2], acc1[3]);
        o1[1] = make_float4(acc1[4], acc1[5], acc1[6], acc1[7]);
        o1[2] = make_float4(acc1[8], acc1[9], acc1[10], acc1[11]);
        o1[3] = make_float4(acc1[12], acc1[13], acc1[14], acc1[15]);
    }
}

// ---------------------------------------------------------------------------
// Kernel 2: sequential RNN scan per user (16 lanes = 16 h-components),
// fused LeakyReLU + Dense(32).  (unchanged from round 1 — ~3 µs)
// ---------------------------------------------------------------------------
__device__ __forceinline__ float tanh_fast(float x) {
    float e = __expf(2.f * x);
    return 1.f - 2.f / (e + 1.f);
}

__global__ __launch_bounds__(64) void k_rnn(
    const float* __restrict__ pre, const int* __restrict__ docid,
    const float* __restrict__ Wh, const float* __restrict__ Wd,
    const float* __restrict__ bd, float* __restrict__ out)
{
    const int tid = threadIdx.x;
    const int l = tid & 15;
    const int u = (blockIdx.x * 64 + tid) >> 4;

    const float* prow = pre + (size_t)u * T_ * H_;
    const int* drow = docid + (size_t)u * T_;

    float wh[16];
#pragma unroll
    for (int k = 0; k < 16; ++k) wh[k] = Wh[((l ^ k) << 4) | l];

    float h = 0.f;

    float pb0 = prow[0 * H_ + l], pb1 = prow[1 * H_ + l],
          pb2 = prow[2 * H_ + l], pb3 = prow[3 * H_ + l];
    int   m0 = drow[0], m1 = drow[1], m2 = drow[2], m3 = drow[3];

    for (int tb = 0; tb < T_; tb += 4) {
#pragma unroll
        for (int s = 0; s < 4; ++s) {
            float p; int m;
            if      (s == 0) { p = pb0; m = m0; }
            else if (s == 1) { p = pb1; m = m1; }
            else if (s == 2) { p = pb2; m = m2; }
            else             { p = pb3; m = m3; }

            int tn = tb + 4 + s; if (tn > T_ - 1) tn = T_ - 1;
            float pn = prow[tn * H_ + l];
            int   mn = drow[tn];
            if      (s == 0) { pb0 = pn; m0 = mn; }
            else if (s == 1) { pb1 = pn; m1 = mn; }
            else if (s == 2) { pb2 = pn; m2 = mn; }
            else             { pb3 = pn; m3 = mn; }

            float a0 = p, a1 = 0.f, a2 = 0.f, a3 = 0.f;
#pragma unroll
            for (int k = 0; k < 16; k += 4) {
                a0 += __shfl_xor(h, k + 0, 16) * wh[k + 0];
                a1 += __shfl_xor(h, k + 1, 16) * wh[k + 1];
                a2 += __shfl_xor(h, k + 2, 16) * wh[k + 2];
                a3 += __shfl_xor(h, k + 3, 16) * wh[k + 3];
            }
            float accv = (a0 + a1) + (a2 + a3);
            float th = tanh_fast(accv);
            h = (m != 0) ? th : h;
        }
    }

    float a = (h >= 0.f) ? h : 0.3f * h;

    float wd0[16], wd1[16];
#pragma unroll
    for (int k = 0; k < 16; ++k) {
        int j = l ^ k;
        wd0[k] = Wd[j * DU_ + l];
        wd1[k] = Wd[j * DU_ + l + 16];
    }
    float o0 = bd[l], o1 = bd[l + 16];
#pragma unroll
    for (int k = 0; k < 16; ++k) {
        float av = __shfl_xor(a, k, 16);
        o0 += av * wd0[k];
        o1 += av * wd1[k];
    }
    out[(size_t)u * DU_ + l] = o0;
    out[(size_t)u * DU_ + l + 16] = o1;
}

// ---------------------------------------------------------------------------
extern "C" void kernel_launch(void* const* d_in, const int* in_sizes, int n_in,
                              void* d_out, int out_size, void* d_ws, size_t ws_size,
                              hipStream_t stream) {
    const float* q     = (const float*)d_in[0];
    const float* f     = (const float*)d_in[1];
    const int*   docid = (const int*)  d_in[2];
    const float* ct    = (const float*)d_in[3];
    const float* emb   = (const float*)d_in[4];
    const float* Wx    = (const float*)d_in[5];
    const float* Wh    = (const float*)d_in[6];
    const float* brnn  = (const float*)d_in[7];
    const float* Wd    = (const float*)d_in[8];
    const float* bd    = (const float*)d_in[9];
    float* out = (float*)d_out;

    float* pre = (float*)d_ws;                   // U*T*H floats = 26.2 MB

    k_pre<<<(U_ * T_) / POS_PER_BLK, THREADS, 0, stream>>>(q, f, docid, ct, emb, Wx, brnn, pre);
    k_rnn<<<(U_ * H_) / 64, 64, 0, stream>>>(pre, docid, Wh, Wd, bd, out);
}